// Round 17
// baseline (277.916 us; speedup 1.0000x reference)
//
#include <hip/hip_runtime.h>
#include <hip/hip_fp16.h>

#define N_NODES 50000
#define N_EDGESx 600000
#define E_TOT   (N_EDGESx + N_NODES)   // 650000
#define NEG_SLOPE 0.2f

typedef _Float16 f16x4 __attribute__((ext_vector_type(4)));
typedef float f32x4 __attribute__((ext_vector_type(4)));
typedef unsigned long long u64;

__device__ __forceinline__ float lrelu(float x) { return x > 0.f ? x : NEG_SLOPE * x; }

// ---------------------------------------------------------------- CSR build
__global__ __launch_bounds__(256) void count_k(const int* __restrict__ ei,
                                               int* __restrict__ counts) {
    int i = blockIdx.x * 256 + threadIdx.x;
    if (i >= E_TOT) return;
    int dst = (i < N_EDGESx) ? ei[N_EDGESx + i] : (i - N_EDGESx);
    atomicAdd(&counts[dst], 1);
}

__global__ __launch_bounds__(1024) void scanA(const int* __restrict__ counts,
                                              int* __restrict__ offs,
                                              int* __restrict__ chunks, int N) {
    __shared__ int sdata[1024];
    int t = threadIdx.x;
    int g = blockIdx.x * 1024 + t;
    int v = (g < N) ? counts[g] : 0;
    sdata[t] = v;
    __syncthreads();
    for (int off = 1; off < 1024; off <<= 1) {
        int x = (t >= off) ? sdata[t - off] : 0;
        __syncthreads();
        sdata[t] += x;
        __syncthreads();
    }
    int incl = sdata[t];
    if (g < N) offs[g] = incl - v;           // exclusive within chunk
    if (t == 1023) chunks[blockIdx.x] = incl;
}

__global__ void scanB(int* chunks, int nch) {
    int lane = threadIdx.x & 63;
    int orig = (lane < nch) ? chunks[lane] : 0;
    int v = orig;
#pragma unroll
    for (int off = 1; off < 64; off <<= 1) {
        int u = __shfl_up(v, off);
        if (lane >= off) v += u;
    }
    if (lane < nch) chunks[lane] = v - orig;  // exclusive
}

__global__ __launch_bounds__(1024) void scanC(int* __restrict__ offs,
                                              const int* __restrict__ chunks, int N) {
    int g = blockIdx.x * 1024 + threadIdx.x;
    if (g < N) offs[g] += chunks[blockIdx.x];
}

__global__ __launch_bounds__(256) void scatter_k(const int* __restrict__ ei,
                                                 const int* __restrict__ offs,
                                                 int* __restrict__ cursor,
                                                 int* __restrict__ edge_src) {
    int i = blockIdx.x * 256 + threadIdx.x;
    if (i >= E_TOT) return;
    int src, dst;
    if (i < N_EDGESx) { src = ei[i]; dst = ei[N_EDGESx + i]; }
    else              { src = dst = i - N_EDGESx; }
    int pos = atomicAdd(&cursor[dst], 1);
    edge_src[offs[dst] + pos] = src;
}

// ---------------------------------------------------------------- W pre-convert (both weights, one launch)
__global__ __launch_bounds__(256) void prepBoth_k(const float* __restrict__ W1,
                                                  const float* __restrict__ W2,
                                                  _Float16* __restrict__ Bt1,
                                                  _Float16* __restrict__ Bt2) {
    int b = blockIdx.x;
    if (b < 32) {                       // W1: K=128, N=256, no BPERM
        constexpr int K = 128, N = 256;
        int q = b * 256 + threadIdx.x;  // q < 8192
        int n = q & (N - 1);
        int k4 = q / N;
        f16x4 v;
#pragma unroll
        for (int i = 0; i < 4; ++i)
            v[i] = (_Float16)W1[(size_t)(k4 * 4 + i) * N + n];
        int idx = n * K + (((k4 >> 1) ^ (n & 15)) << 3) + ((k4 & 1) << 2);
        *(f16x4*)&Bt1[idx] = v;
    } else {                            // W2: K=256, N=64, BPERM (head interleave)
        constexpr int K = 256, N = 64;
        int q = (b - 32) * 256 + threadIdx.x;  // q < 4096
        int n = q & (N - 1);
        int k4 = q / N;
        f16x4 v;
#pragma unroll
        for (int i = 0; i < 4; ++i) {
            int kg = k4 * 4 + i;
            int krow = (kg & 3) * 64 + (kg >> 2);
            v[i] = (_Float16)W2[(size_t)krow * N + n];
        }
        int idx = n * K + (((k4 >> 1) ^ (n & 15)) << 3) + ((k4 & 1) << 2);
        *(f16x4*)&Bt2[idx] = v;
    }
}

// ---------------------------------------------------------------- MFMA GEMM (+fused alpha dots)
template<int K, int N, int CPW, typename AT, int CPERM, int ALPHA>
__global__ __launch_bounds__(256, 2) void gemm_mfma(const AT* __restrict__ A,
                                                    const _Float16* __restrict__ Bt,
                                                    _Float16* __restrict__ C,
                                                    const float* __restrict__ asrc,
                                                    const float* __restrict__ adst,
                                                    float* __restrict__ as_o,
                                                    float* __restrict__ ad_o, int M) {
    __shared__ __align__(16) _Float16 Ah[64 * K];
    __shared__ __align__(16) _Float16 Bh[N * K];
    const int t = threadIdx.x;
    const int row0 = blockIdx.x * 64;

#pragma unroll
    for (int q = t; q < 64 * K / 4; q += 256) {
        int r = q / (K / 4);
        int k4 = q % (K / 4);
        f16x4 v;
        int grow = row0 + r;
        if (grow < M) {
            if constexpr (sizeof(AT) == 4) {
                float4 f = *(const float4*)(A + (size_t)grow * K + k4 * 4);
                v[0] = (_Float16)f.x; v[1] = (_Float16)f.y;
                v[2] = (_Float16)f.z; v[3] = (_Float16)f.w;
            } else {
                v = *(const f16x4*)(A + (size_t)grow * K + k4 * 4);
            }
        } else {
            v[0] = v[1] = v[2] = v[3] = (_Float16)0.f;
        }
        int idx = r * K + (((k4 >> 1) ^ (r & 15)) << 3) + ((k4 & 1) << 2);
        *(f16x4*)&Ah[idx] = v;
    }
    // B staging: pure 16B copy (layout pre-swizzled in prepBoth_k)
#pragma unroll
    for (int q = t; q < N * K / 8; q += 256)
        ((uint4*)Bh)[q] = ((const uint4*)Bt)[q];
    __syncthreads();

    const int w = t >> 6;
    const int l = t & 63;
    const int lr = l & 15;
    const int g = l >> 4;

    f32x4 acc[4][CPW];
#pragma unroll
    for (int mt = 0; mt < 4; ++mt)
#pragma unroll
        for (int nt = 0; nt < CPW; ++nt)
            acc[mt][nt] = (f32x4){0.f, 0.f, 0.f, 0.f};

#pragma unroll
    for (int ks = 0; ks < K / 16; ++ks) {
        int k = ks * 16 + g * 4;
        f16x4 a[4], b[CPW];
#pragma unroll
        for (int mt = 0; mt < 4; ++mt) {
            int r = mt * 16 + lr;
            a[mt] = *(const f16x4*)&Ah[r * K + (((k >> 3) ^ (r & 15)) << 3) + (k & 7)];
        }
#pragma unroll
        for (int nt = 0; nt < CPW; ++nt) {
            int n = (w * CPW + nt) * 16 + lr;
            b[nt] = *(const f16x4*)&Bh[n * K + (((k >> 3) ^ (n & 15)) << 3) + (k & 7)];
        }
#pragma unroll
        for (int mt = 0; mt < 4; ++mt)
#pragma unroll
            for (int nt = 0; nt < CPW; ++nt)
                acc[mt][nt] = __builtin_amdgcn_mfma_f32_16x16x16f16(a[mt], b[nt],
                                                                   acc[mt][nt], 0, 0, 0);
    }

    if constexpr (CPERM) {
        // Ah is dead after the MFMA loop: reuse for a_src/a_dst staging + psums.
        float* A_s  = (float*)Ah;          // [256]
        float* A_d  = A_s + 256;           // [256]
        float* psum = A_d + 256;           // [64][4][8] = 2048 floats
        __syncthreads();
        _Float16* Cs = Bh;
#pragma unroll
        for (int mt = 0; mt < 4; ++mt)
#pragma unroll
            for (int q = 0; q < 4; ++q) {
                int row = mt * 16 + g * 4 + q;
#pragma unroll
                for (int nt = 0; nt < CPW; ++nt) {
                    int gcol = (w * CPW + nt) * 16 + lr;
                    int ocol = ((gcol & 63) << 2) | (gcol >> 6);
                    Cs[row * N + ocol] = (_Float16)acc[mt][nt][q];
                }
            }
        if constexpr (ALPHA == 1) { A_s[t] = asrc[t]; A_d[t] = adst[t]; }
        __syncthreads();
#pragma unroll
        for (int q = t; q < 64 * N / 8; q += 256) {
            int row = q / (N / 8);
            int c8 = q % (N / 8);
            int grow = row0 + row;
            if (grow < M)
                *(float4*)(C + (size_t)grow * N + c8 * 8) =
                    *(const float4*)&Cs[row * N + c8 * 8];
        }
        if constexpr (ALPHA == 1) {
            int row = t & 63, qr = t >> 6;
            float s[4] = {}, d[4] = {};
#pragma unroll
            for (int j = 0; j < 16; ++j) {
                int c = qr * 16 + j;
                union { uint2 u; __half h[4]; } U;
                U.u = *(const uint2*)&Cs[row * 256 + c * 4];
#pragma unroll
                for (int h = 0; h < 4; ++h) {
                    float f = __half2float(U.h[h]);
                    s[h] += f * A_s[h * 64 + c];
                    d[h] += f * A_d[h * 64 + c];
                }
            }
            float* ps = psum + (row * 4 + qr) * 8;
#pragma unroll
            for (int h = 0; h < 4; ++h) { ps[h] = s[h]; ps[4 + h] = d[h]; }
            __syncthreads();
            if (t < 64 && row0 + t < M) {
                float4 S = make_float4(0.f, 0.f, 0.f, 0.f);
                float4 D = make_float4(0.f, 0.f, 0.f, 0.f);
#pragma unroll
                for (int q2 = 0; q2 < 4; ++q2) {
                    float* ps2 = psum + (t * 4 + q2) * 8;
                    S.x += ps2[0]; S.y += ps2[1]; S.z += ps2[2]; S.w += ps2[3];
                    D.x += ps2[4]; D.y += ps2[5]; D.z += ps2[6]; D.w += ps2[7];
                }
                *(float4*)(as_o + (size_t)(row0 + t) * 4) = S;
                *(float4*)(ad_o + (size_t)(row0 + t) * 4) = D;
            }
        }
    } else {
#pragma unroll
        for (int mt = 0; mt < 4; ++mt)
#pragma unroll
            for (int q = 0; q < 4; ++q) {
                int grow = row0 + mt * 16 + g * 4 + q;
                if (grow >= M) continue;
#pragma unroll
                for (int nt = 0; nt < CPW; ++nt) {
                    int gcol = (w * CPW + nt) * 16 + lr;
                    C[(size_t)grow * N + gcol] = (_Float16)acc[mt][nt][q];
                }
            }
        if constexpr (ALPHA == 2) {
            __half* Ch  = (__half*)Ah;            // [64][64] = 8 KB
            float*  A_s = (float*)(Ch + 64 * 64); // [64]
            float*  A_d = A_s + 64;               // [64]
            float*  psum = A_d + 64;              // [64][4][2]
            __syncthreads();
#pragma unroll
            for (int mt = 0; mt < 4; ++mt)
#pragma unroll
                for (int q = 0; q < 4; ++q) {
                    int row = mt * 16 + g * 4 + q;
                    Ch[row * 64 + w * 16 + lr] = __float2half(acc[mt][0][q]);
                }
            if (t < 64) { A_s[t] = asrc[t]; A_d[t] = adst[t]; }
            __syncthreads();
            int row = t & 63, qr = t >> 6;
            float s = 0.f, d = 0.f;
#pragma unroll
            for (int j = 0; j < 16; ++j) {
                int c = qr * 16 + j;
                float f = __half2float(Ch[row * 64 + c]);
                s += f * A_s[c];
                d += f * A_d[c];
            }
            psum[(row * 4 + qr) * 2]     = s;
            psum[(row * 4 + qr) * 2 + 1] = d;
            __syncthreads();
            if (t < 64 && row0 + t < M) {
                float S = 0.f, D = 0.f;
#pragma unroll
                for (int q2 = 0; q2 < 4; ++q2) {
                    S += psum[(t * 4 + q2) * 2];
                    D += psum[(t * 4 + q2) * 2 + 1];
                }
                as_o[row0 + t] = S;
                ad_o[row0 + t] = D;
            }
        }
    }
}

// ---------------------------------------------------------------- stats + weight write (fp16 w, nt streaming)
__global__ __launch_bounds__(256) void stats1w_k(const int* __restrict__ edge_src,
                                                 const float* __restrict__ as1,
                                                 const float* __restrict__ ad1,
                                                 const int* __restrict__ offs,
                                                 const int* __restrict__ counts,
                                                 __half* __restrict__ w4, int N) {
    int lane = threadIdx.x & 63;
    int n = blockIdx.x * 4 + (threadIdx.x >> 6);
    if (n >= N) return;
    int start = offs[n];
    int end = start + counts[n];
    int h4 = lane & 3;
    float4 ad = *(const float4*)(ad1 + (size_t)n * 4);
    float adh = h4 == 0 ? ad.x : h4 == 1 ? ad.y : h4 == 2 ? ad.z : ad.w;
    float m = -1e30f, s = 0.f;
    for (int p = start + (lane >> 2); p < end; p += 16) {
        float e = lrelu(as1[(size_t)__builtin_nontemporal_load(edge_src + p) * 4 + h4] + adh);
        float nm = fmaxf(m, e);
        s = s * __expf(m - nm) + __expf(e - nm);
        m = nm;
    }
#pragma unroll
    for (int i = 0; i < 4; ++i) {                 // reduce lanes with same h4
        int msk = 4 << i;
        float om = __shfl_xor(m, msk);
        float os = __shfl_xor(s, msk);
        float nm = fmaxf(m, om);
        s = s * __expf(m - nm) + os * __expf(om - nm);
        m = nm;
    }
    float rcp = 1.f / (s + 1e-16f);
    float4 mh = make_float4(__shfl(m, 0), __shfl(m, 1), __shfl(m, 2), __shfl(m, 3));
    float4 rs = make_float4(__shfl(rcp, 0), __shfl(rcp, 1), __shfl(rcp, 2), __shfl(rcp, 3));
    for (int p = start + lane; p < end; p += 64) {
        float4 a = *(const float4*)(as1 + (size_t)edge_src[p] * 4);
        union { u64 u; __half h[4]; } W;
        W.h[0] = __float2half(__expf(lrelu(a.x + ad.x) - mh.x) * rs.x);
        W.h[1] = __float2half(__expf(lrelu(a.y + ad.y) - mh.y) * rs.y);
        W.h[2] = __float2half(__expf(lrelu(a.z + ad.z) - mh.z) * rs.z);
        W.h[3] = __float2half(__expf(lrelu(a.w + ad.w) - mh.w) * rs.w);
        __builtin_nontemporal_store(W.u, (u64*)(w4 + (size_t)p * 4));
    }
}

// ---------------------------------------------------------------- aggregate layer 1 (R12-proven form + nt hints)
__global__ __launch_bounds__(256) void agg1_k(const __half* __restrict__ h1,
                                              const __half* __restrict__ w4,
                                              const int* __restrict__ edge_src,
                                              const int* __restrict__ offs,
                                              const int* __restrict__ counts,
                                              const float* __restrict__ b1,
                                              __half* __restrict__ out1, int N) {
    int lane = threadIdx.x & 63;
    int n = blockIdx.x * 4 + (threadIdx.x >> 6);
    if (n >= N) return;
    int start = offs[n];
    int end = start + counts[n];
    float acc0 = 0.f, acc1 = 0.f, acc2 = 0.f, acc3 = 0.f;
    int p = start;
    for (; p + 7 < end; p += 8) {
        int s[8]; u64 ww[8]; uint2 hw[8];
#pragma unroll
        for (int i = 0; i < 8; ++i) s[i] = __builtin_nontemporal_load(edge_src + p + i);
#pragma unroll
        for (int i = 0; i < 8; ++i) ww[i] = __builtin_nontemporal_load((const u64*)(w4 + (size_t)(p + i) * 4));
#pragma unroll
        for (int i = 0; i < 8; ++i) hw[i] = *(const uint2*)(h1 + (size_t)s[i] * 256 + lane * 4);
#pragma unroll
        for (int i = 0; i < 8; ++i) {
            union { uint2 u; __half h[4]; } U;
            union { u64 u; __half h[4]; } W;
            U.u = hw[i]; W.u = ww[i];
            acc0 += __half2float(U.h[0]) * __half2float(W.h[0]);
            acc1 += __half2float(U.h[1]) * __half2float(W.h[1]);
            acc2 += __half2float(U.h[2]) * __half2float(W.h[2]);
            acc3 += __half2float(U.h[3]) * __half2float(W.h[3]);
        }
    }
    for (; p < end; ++p) {
        int s0 = edge_src[p];
        union { uint2 u; __half h[4]; } U0;
        union { u64 u; __half h[4]; } W0;
        W0.u = *(const u64*)(w4 + (size_t)p * 4);
        U0.u = *(const uint2*)(h1 + (size_t)s0 * 256 + lane * 4);
        acc0 += __half2float(U0.h[0]) * __half2float(W0.h[0]);
        acc1 += __half2float(U0.h[1]) * __half2float(W0.h[1]);
        acc2 += __half2float(U0.h[2]) * __half2float(W0.h[2]);
        acc3 += __half2float(U0.h[3]) * __half2float(W0.h[3]);
    }
    union { u64 u; __half h[4]; } O;
    O.h[0] = __float2half(fmaxf(acc0 + b1[lane], 0.f));
    O.h[1] = __float2half(fmaxf(acc1 + b1[64 + lane], 0.f));
    O.h[2] = __float2half(fmaxf(acc2 + b1[128 + lane], 0.f));
    O.h[3] = __float2half(fmaxf(acc3 + b1[192 + lane], 0.f));
    __builtin_nontemporal_store(O.u, (u64*)(out1 + (size_t)n * 256 + lane * 4));
}

// ---------------------------------------------------------------- aggregate layer 2 (+fused softmax stats)
// 2 nodes per wave, 32 lanes/node.  Pass 1: online (m,s) over the segment,
// 5-step butterfly within the 32-lane group.  Pass 2: gather-FMA with w
// computed ONCE per edge (lane l&7 computes edge p+(l&7); __shfl broadcasts).
__global__ __launch_bounds__(256) void agg2f_k(const __half* __restrict__ h2,
                                               const float* __restrict__ as2,
                                               const float* __restrict__ ad2,
                                               const int* __restrict__ edge_src,
                                               const int* __restrict__ offs,
                                               const int* __restrict__ counts,
                                               const float* __restrict__ b2,
                                               float* __restrict__ out2, int N) {
    int wl = threadIdx.x & 63;
    int l32 = threadIdx.x & 31;
    int n = blockIdx.x * 8 + (threadIdx.x >> 5);
    if (n >= N) return;
    int start = offs[n];
    int end = start + counts[n];
    float adn = ad2[n];
    float m = -1e30f, s = 0.f;
    for (int p = start + l32; p < end; p += 32) {
        float e = lrelu(as2[edge_src[p]] + adn);
        float nm = fmaxf(m, e);
        s = s * __expf(m - nm) + __expf(e - nm);
        m = nm;
    }
#pragma unroll
    for (int i = 0; i < 5; ++i) {     // butterfly stays within the 32-lane group
        int msk = 1 << i;
        float om = __shfl_xor(m, msk);
        float os = __shfl_xor(s, msk);
        float nm = fmaxf(m, om);
        s = s * __expf(m - nm) + os * __expf(om - nm);
        m = nm;
    }
    float rn = 1.f / (s + 1e-16f);
    int base = wl & 32;
    float ax = 0.f, ay = 0.f;
    int p = start;
    for (; p + 7 < end; p += 8) {
        int se = __builtin_nontemporal_load(edge_src + p + (l32 & 7));
        float wv = __expf(lrelu(as2[se] + adn) - m) * rn;
        int sidx[8]; __half2 hv8[8];
#pragma unroll
        for (int i = 0; i < 8; ++i) sidx[i] = edge_src[p + i];
#pragma unroll
        for (int i = 0; i < 8; ++i)
            hv8[i] = *(const __half2*)(h2 + (size_t)sidx[i] * 64 + l32 * 2);
#pragma unroll
        for (int i = 0; i < 8; ++i) {
            float w = __shfl(wv, base + i);
            float2 f = __half22float2(hv8[i]);
            ax += f.x * w; ay += f.y * w;
        }
    }
    for (; p < end; ++p) {
        int s0 = edge_src[p];
        float w = __expf(lrelu(as2[s0] + adn) - m) * rn;
        float2 f = __half22float2(*(const __half2*)(h2 + (size_t)s0 * 64 + l32 * 2));
        ax += f.x * w; ay += f.y * w;
    }
    union { double d; float2 f; } O;
    O.f.x = fmaxf(ax + b2[l32 * 2], 0.f);
    O.f.y = fmaxf(ay + b2[l32 * 2 + 1], 0.f);
    __builtin_nontemporal_store(O.d, (double*)(out2 + (size_t)n * 64 + l32 * 2));
}

// ---------------------------------------------------------------- classifier head
__global__ __launch_bounds__(256) void cls_k(const float* __restrict__ hin,
                                             const float* __restrict__ Wc1,
                                             const float* __restrict__ bc1,
                                             const float* __restrict__ Wc2,
                                             const float* __restrict__ bc2,
                                             float* __restrict__ out, int N) {
    __shared__ float W1s[64 * 32];
    __shared__ float W2s[64];
    __shared__ float b1s[32];
    __shared__ float b2s[2];
    __shared__ float z[8][33];
    int t = threadIdx.x;
    for (int i = t; i < 2048; i += 256) W1s[i] = Wc1[i];
    if (t < 64) W2s[t] = Wc2[t];
    if (t < 32) b1s[t] = bc1[t];
    if (t < 2)  b2s[t] = bc2[t];
    __syncthreads();
    int nl = t >> 5, j = t & 31;
    int n = blockIdx.x * 8 + nl;
    float acc = b1s[j];
    if (n < N) {
        const float* hr = hin + (size_t)n * 64;
#pragma unroll 8
        for (int l = 0; l < 64; ++l) acc += hr[l] * W1s[l * 32 + j];
    }
    z[nl][j] = fmaxf(acc, 0.f);
    __syncthreads();
    if (j < 2 && n < N) {
        float o = b2s[j];
#pragma unroll
        for (int q = 0; q < 32; ++q) o += z[nl][q] * W2s[q * 2 + j];
        out[(size_t)n * 2 + j] = o;
    }
}

// ---------------------------------------------------------------- launch
extern "C" void kernel_launch(void* const* d_in, const int* in_sizes, int n_in,
                              void* d_out, int out_size, void* d_ws, size_t ws_size,
                              hipStream_t stream) {
    const float* x      = (const float*)d_in[0];
    const int*   ei     = (const int*)d_in[1];
    const float* W1     = (const float*)d_in[2];
    const float* a_src1 = (const float*)d_in[3];
    const float* a_dst1 = (const float*)d_in[4];
    const float* b1     = (const float*)d_in[5];
    const float* W2     = (const float*)d_in[6];
    const float* a_src2 = (const float*)d_in[7];
    const float* a_dst2 = (const float*)d_in[8];
    const float* b2     = (const float*)d_in[9];
    const float* Wc1    = (const float*)d_in[10];
    const float* bc1    = (const float*)d_in[11];
    const float* Wc2    = (const float*)d_in[12];
    const float* bc2    = (const float*)d_in[13];

    char* ws = (char*)d_ws;
    size_t off = 0;
    auto alloc = [&](size_t bytes) -> void* {
        void* p = ws + off;
        off += (bytes + 255) & ~(size_t)255;
        return p;
    };
    int*       counts   = (int*)alloc((size_t)N_NODES * 4);   // contiguous with cursor
    int*       cursor   = (int*)alloc((size_t)N_NODES * 4);
    int*       offs     = (int*)alloc((size_t)N_NODES * 4);
    int*       chunks   = (int*)alloc(256);
    int*       edge_src = (int*)alloc((size_t)E_TOT * 4);
    float*     as1      = (float*)alloc((size_t)N_NODES * 16);
    float*     ad1      = (float*)alloc((size_t)N_NODES * 16);
    float*     as2      = (float*)alloc((size_t)N_NODES * 4);
    float*     ad2      = (float*)alloc((size_t)N_NODES * 4);
    __half*    w4       = (__half*)alloc((size_t)E_TOT * 8);        // fp16 L1 weights
    _Float16*  Bt1      = (_Float16*)alloc((size_t)256 * 128 * 2);  // prepped W1
    _Float16*  Bt2      = (_Float16*)alloc((size_t)64 * 256 * 2);   // prepped W2
    __half*    h1h      = (__half*)alloc((size_t)N_NODES * 256 * 2);  // interleaved; reused as h2
    __half*    out1h    = (__half*)alloc((size_t)N_NODES * 256 * 2);  // interleaved
    float*     out2     = (float*)alloc((size_t)N_NODES * 64 * 4);
    __half*    h2h  = h1h;       // h1 dead after agg1

    const int EB = (E_TOT + 255) / 256;
    const int NB4 = (N_NODES + 3) / 4;
    const int NB8 = (N_NODES + 7) / 8;
    const int NCH = (N_NODES + 1023) / 1024;  // 49
    const int MB = (N_NODES + 63) / 64;       // 782

    // counts and cursor are adjacent 256-aligned allocs: one memset covers both
    hipMemsetAsync(counts, 0, (char*)cursor - (char*)counts + (size_t)N_NODES * 4, stream);

    count_k<<<EB, 256, 0, stream>>>(ei, counts);
    scanA<<<NCH, 1024, 0, stream>>>(counts, offs, chunks, N_NODES);
    scanB<<<1, 64, 0, stream>>>(chunks, NCH);
    scanC<<<NCH, 1024, 0, stream>>>(offs, chunks, N_NODES);
    scatter_k<<<EB, 256, 0, stream>>>(ei, offs, cursor, edge_src);

    prepBoth_k<<<48, 256, 0, stream>>>(W1, W2, Bt1, Bt2);

    gemm_mfma<128, 256, 4, float, 1, 1><<<MB, 256, 0, stream>>>(
        x, Bt1, (_Float16*)h1h, a_src1, a_dst1, as1, ad1, N_NODES);
    stats1w_k<<<NB4, 256, 0, stream>>>(edge_src, as1, ad1, offs, counts, w4, N_NODES);
    agg1_k<<<NB4, 256, 0, stream>>>(h1h, w4, edge_src, offs, counts, b1, out1h, N_NODES);

    gemm_mfma<256, 64, 1, _Float16, 0, 2><<<MB, 256, 0, stream>>>(
        (const _Float16*)out1h, Bt2, (_Float16*)h2h, a_src2, a_dst2, as2, ad2, N_NODES);
    agg2f_k<<<NB8, 256, 0, stream>>>(h2h, as2, ad2, edge_src, offs, counts, b2, out2, N_NODES);

    cls_k<<<N_NODES / 8, 256, 0, stream>>>(out2, Wc1, bc1, Wc2, bc2, (float*)d_out, N_NODES);
}

// Round 18
// 257.183 us; speedup vs baseline: 1.0806x; 1.0806x over previous
//
#include <hip/hip_runtime.h>
#include <hip/hip_fp16.h>

#define N_NODES 50000
#define N_EDGESx 600000
#define E_TOT   (N_EDGESx + N_NODES)   // 650000
#define NEG_SLOPE 0.2f

typedef _Float16 f16x4 __attribute__((ext_vector_type(4)));
typedef float f32x4 __attribute__((ext_vector_type(4)));

__device__ __forceinline__ float lrelu(float x) { return x > 0.f ? x : NEG_SLOPE * x; }

// ---------------------------------------------------------------- CSR build
__global__ __launch_bounds__(256) void count_k(const int* __restrict__ ei,
                                               int* __restrict__ counts) {
    int i = blockIdx.x * 256 + threadIdx.x;
    if (i >= E_TOT) return;
    int dst = (i < N_EDGESx) ? ei[N_EDGESx + i] : (i - N_EDGESx);
    atomicAdd(&counts[dst], 1);
}

__global__ __launch_bounds__(1024) void scanA(const int* __restrict__ counts,
                                              int* __restrict__ offs,
                                              int* __restrict__ chunks, int N) {
    __shared__ int sdata[1024];
    int t = threadIdx.x;
    int g = blockIdx.x * 1024 + t;
    int v = (g < N) ? counts[g] : 0;
    sdata[t] = v;
    __syncthreads();
    for (int off = 1; off < 1024; off <<= 1) {
        int x = (t >= off) ? sdata[t - off] : 0;
        __syncthreads();
        sdata[t] += x;
        __syncthreads();
    }
    int incl = sdata[t];
    if (g < N) offs[g] = incl - v;           // exclusive within chunk
    if (t == 1023) chunks[blockIdx.x] = incl;
}

__global__ void scanB(int* chunks, int nch) {
    int lane = threadIdx.x & 63;
    int orig = (lane < nch) ? chunks[lane] : 0;
    int v = orig;
#pragma unroll
    for (int off = 1; off < 64; off <<= 1) {
        int u = __shfl_up(v, off);
        if (lane >= off) v += u;
    }
    if (lane < nch) chunks[lane] = v - orig;  // exclusive
}

__global__ __launch_bounds__(1024) void scanC(int* __restrict__ offs,
                                              const int* __restrict__ chunks, int N) {
    int g = blockIdx.x * 1024 + threadIdx.x;
    if (g < N) offs[g] += chunks[blockIdx.x];
}

__global__ __launch_bounds__(256) void scatter_k(const int* __restrict__ ei,
                                                 const int* __restrict__ offs,
                                                 int* __restrict__ cursor,
                                                 int* __restrict__ edge_src) {
    int i = blockIdx.x * 256 + threadIdx.x;
    if (i >= E_TOT) return;
    int src, dst;
    if (i < N_EDGESx) { src = ei[i]; dst = ei[N_EDGESx + i]; }
    else              { src = dst = i - N_EDGESx; }
    int pos = atomicAdd(&cursor[dst], 1);
    edge_src[offs[dst] + pos] = src;
}

// ---------------------------------------------------------------- W pre-convert (both weights, one launch)
__global__ __launch_bounds__(256) void prepBoth_k(const float* __restrict__ W1,
                                                  const float* __restrict__ W2,
                                                  _Float16* __restrict__ Bt1,
                                                  _Float16* __restrict__ Bt2) {
    int b = blockIdx.x;
    if (b < 32) {                       // W1: K=128, N=256, no BPERM
        constexpr int K = 128, N = 256;
        int q = b * 256 + threadIdx.x;  // q < 8192
        int n = q & (N - 1);
        int k4 = q / N;
        f16x4 v;
#pragma unroll
        for (int i = 0; i < 4; ++i)
            v[i] = (_Float16)W1[(size_t)(k4 * 4 + i) * N + n];
        int idx = n * K + (((k4 >> 1) ^ (n & 15)) << 3) + ((k4 & 1) << 2);
        *(f16x4*)&Bt1[idx] = v;
    } else {                            // W2: K=256, N=64, BPERM (head interleave)
        constexpr int K = 256, N = 64;
        int q = (b - 32) * 256 + threadIdx.x;  // q < 4096
        int n = q & (N - 1);
        int k4 = q / N;
        f16x4 v;
#pragma unroll
        for (int i = 0; i < 4; ++i) {
            int kg = k4 * 4 + i;
            int krow = (kg & 3) * 64 + (kg >> 2);
            v[i] = (_Float16)W2[(size_t)krow * N + n];
        }
        int idx = n * K + (((k4 >> 1) ^ (n & 15)) << 3) + ((k4 & 1) << 2);
        *(f16x4*)&Bt2[idx] = v;
    }
}

// ---------------------------------------------------------------- MFMA GEMM (+fused alpha dots)
template<int K, int N, int CPW, typename AT, int CPERM, int ALPHA>
__global__ __launch_bounds__(256, 2) void gemm_mfma(const AT* __restrict__ A,
                                                    const _Float16* __restrict__ Bt,
                                                    _Float16* __restrict__ C,
                                                    const float* __restrict__ asrc,
                                                    const float* __restrict__ adst,
                                                    float* __restrict__ as_o,
                                                    float* __restrict__ ad_o, int M) {
    __shared__ __align__(16) _Float16 Ah[64 * K];
    __shared__ __align__(16) _Float16 Bh[N * K];
    const int t = threadIdx.x;
    const int row0 = blockIdx.x * 64;

#pragma unroll
    for (int q = t; q < 64 * K / 4; q += 256) {
        int r = q / (K / 4);
        int k4 = q % (K / 4);
        f16x4 v;
        int grow = row0 + r;
        if (grow < M) {
            if constexpr (sizeof(AT) == 4) {
                float4 f = *(const float4*)(A + (size_t)grow * K + k4 * 4);
                v[0] = (_Float16)f.x; v[1] = (_Float16)f.y;
                v[2] = (_Float16)f.z; v[3] = (_Float16)f.w;
            } else {
                v = *(const f16x4*)(A + (size_t)grow * K + k4 * 4);
            }
        } else {
            v[0] = v[1] = v[2] = v[3] = (_Float16)0.f;
        }
        int idx = r * K + (((k4 >> 1) ^ (r & 15)) << 3) + ((k4 & 1) << 2);
        *(f16x4*)&Ah[idx] = v;
    }
    // B staging: pure 16B copy (layout pre-swizzled in prepBoth_k)
#pragma unroll
    for (int q = t; q < N * K / 8; q += 256)
        ((uint4*)Bh)[q] = ((const uint4*)Bt)[q];
    __syncthreads();

    const int w = t >> 6;
    const int l = t & 63;
    const int lr = l & 15;
    const int g = l >> 4;

    f32x4 acc[4][CPW];
#pragma unroll
    for (int mt = 0; mt < 4; ++mt)
#pragma unroll
        for (int nt = 0; nt < CPW; ++nt)
            acc[mt][nt] = (f32x4){0.f, 0.f, 0.f, 0.f};

#pragma unroll
    for (int ks = 0; ks < K / 16; ++ks) {
        int k = ks * 16 + g * 4;
        f16x4 a[4], b[CPW];
#pragma unroll
        for (int mt = 0; mt < 4; ++mt) {
            int r = mt * 16 + lr;
            a[mt] = *(const f16x4*)&Ah[r * K + (((k >> 3) ^ (r & 15)) << 3) + (k & 7)];
        }
#pragma unroll
        for (int nt = 0; nt < CPW; ++nt) {
            int n = (w * CPW + nt) * 16 + lr;
            b[nt] = *(const f16x4*)&Bh[n * K + (((k >> 3) ^ (n & 15)) << 3) + (k & 7)];
        }
#pragma unroll
        for (int mt = 0; mt < 4; ++mt)
#pragma unroll
            for (int nt = 0; nt < CPW; ++nt)
                acc[mt][nt] = __builtin_amdgcn_mfma_f32_16x16x16f16(a[mt], b[nt],
                                                                   acc[mt][nt], 0, 0, 0);
    }

    if constexpr (CPERM) {
        // Ah is dead after the MFMA loop: reuse for a_src/a_dst staging + psums.
        float* A_s  = (float*)Ah;          // [256]
        float* A_d  = A_s + 256;           // [256]
        float* psum = A_d + 256;           // [64][4][8] = 2048 floats
        __syncthreads();
        _Float16* Cs = Bh;
#pragma unroll
        for (int mt = 0; mt < 4; ++mt)
#pragma unroll
            for (int q = 0; q < 4; ++q) {
                int row = mt * 16 + g * 4 + q;
#pragma unroll
                for (int nt = 0; nt < CPW; ++nt) {
                    int gcol = (w * CPW + nt) * 16 + lr;
                    int ocol = ((gcol & 63) << 2) | (gcol >> 6);
                    Cs[row * N + ocol] = (_Float16)acc[mt][nt][q];
                }
            }
        if constexpr (ALPHA == 1) { A_s[t] = asrc[t]; A_d[t] = adst[t]; }
        __syncthreads();
#pragma unroll
        for (int q = t; q < 64 * N / 8; q += 256) {
            int row = q / (N / 8);
            int c8 = q % (N / 8);
            int grow = row0 + row;
            if (grow < M)
                *(float4*)(C + (size_t)grow * N + c8 * 8) =
                    *(const float4*)&Cs[row * N + c8 * 8];
        }
        if constexpr (ALPHA == 1) {
            int row = t & 63, qr = t >> 6;
            float s[4] = {}, d[4] = {};
#pragma unroll
            for (int j = 0; j < 16; ++j) {
                int c = qr * 16 + j;
                union { uint2 u; __half h[4]; } U;
                U.u = *(const uint2*)&Cs[row * 256 + c * 4];
#pragma unroll
                for (int h = 0; h < 4; ++h) {
                    float f = __half2float(U.h[h]);
                    s[h] += f * A_s[h * 64 + c];
                    d[h] += f * A_d[h * 64 + c];
                }
            }
            float* ps = psum + (row * 4 + qr) * 8;
#pragma unroll
            for (int h = 0; h < 4; ++h) { ps[h] = s[h]; ps[4 + h] = d[h]; }
            __syncthreads();
            if (t < 64 && row0 + t < M) {
                float4 S = make_float4(0.f, 0.f, 0.f, 0.f);
                float4 D = make_float4(0.f, 0.f, 0.f, 0.f);
#pragma unroll
                for (int q2 = 0; q2 < 4; ++q2) {
                    float* ps2 = psum + (t * 4 + q2) * 8;
                    S.x += ps2[0]; S.y += ps2[1]; S.z += ps2[2]; S.w += ps2[3];
                    D.x += ps2[4]; D.y += ps2[5]; D.z += ps2[6]; D.w += ps2[7];
                }
                *(float4*)(as_o + (size_t)(row0 + t) * 4) = S;
                *(float4*)(ad_o + (size_t)(row0 + t) * 4) = D;
            }
        }
    } else {
#pragma unroll
        for (int mt = 0; mt < 4; ++mt)
#pragma unroll
            for (int q = 0; q < 4; ++q) {
                int grow = row0 + mt * 16 + g * 4 + q;
                if (grow >= M) continue;
#pragma unroll
                for (int nt = 0; nt < CPW; ++nt) {
                    int gcol = (w * CPW + nt) * 16 + lr;
                    C[(size_t)grow * N + gcol] = (_Float16)acc[mt][nt][q];
                }
            }
        if constexpr (ALPHA == 2) {
            __half* Ch  = (__half*)Ah;            // [64][64] = 8 KB
            float*  A_s = (float*)(Ch + 64 * 64); // [64]
            float*  A_d = A_s + 64;               // [64]
            float*  psum = A_d + 64;              // [64][4][2]
            __syncthreads();
#pragma unroll
            for (int mt = 0; mt < 4; ++mt)
#pragma unroll
                for (int q = 0; q < 4; ++q) {
                    int row = mt * 16 + g * 4 + q;
                    Ch[row * 64 + w * 16 + lr] = __float2half(acc[mt][0][q]);
                }
            if (t < 64) { A_s[t] = asrc[t]; A_d[t] = adst[t]; }
            __syncthreads();
            int row = t & 63, qr = t >> 6;
            float s = 0.f, d = 0.f;
#pragma unroll
            for (int j = 0; j < 16; ++j) {
                int c = qr * 16 + j;
                float f = __half2float(Ch[row * 64 + c]);
                s += f * A_s[c];
                d += f * A_d[c];
            }
            psum[(row * 4 + qr) * 2]     = s;
            psum[(row * 4 + qr) * 2 + 1] = d;
            __syncthreads();
            if (t < 64 && row0 + t < M) {
                float S = 0.f, D = 0.f;
#pragma unroll
                for (int q2 = 0; q2 < 4; ++q2) {
                    S += psum[(t * 4 + q2) * 2];
                    D += psum[(t * 4 + q2) * 2 + 1];
                }
                as_o[row0 + t] = S;
                ad_o[row0 + t] = D;
            }
        }
    }
}

// ---------------------------------------------------------------- stats + weight write (fp16 w)
__global__ __launch_bounds__(256) void stats1w_k(const int* __restrict__ edge_src,
                                                 const float* __restrict__ as1,
                                                 const float* __restrict__ ad1,
                                                 const int* __restrict__ offs,
                                                 const int* __restrict__ counts,
                                                 __half* __restrict__ w4, int N) {
    int lane = threadIdx.x & 63;
    int n = blockIdx.x * 4 + (threadIdx.x >> 6);
    if (n >= N) return;
    int start = offs[n];
    int end = start + counts[n];
    int h4 = lane & 3;
    float4 ad = *(const float4*)(ad1 + (size_t)n * 4);
    float adh = h4 == 0 ? ad.x : h4 == 1 ? ad.y : h4 == 2 ? ad.z : ad.w;
    float m = -1e30f, s = 0.f;
    for (int p = start + (lane >> 2); p < end; p += 16) {
        float e = lrelu(as1[(size_t)edge_src[p] * 4 + h4] + adh);
        float nm = fmaxf(m, e);
        s = s * __expf(m - nm) + __expf(e - nm);
        m = nm;
    }
#pragma unroll
    for (int i = 0; i < 4; ++i) {                 // reduce lanes with same h4
        int msk = 4 << i;
        float om = __shfl_xor(m, msk);
        float os = __shfl_xor(s, msk);
        float nm = fmaxf(m, om);
        s = s * __expf(m - nm) + os * __expf(om - nm);
        m = nm;
    }
    float rcp = 1.f / (s + 1e-16f);
    float4 mh = make_float4(__shfl(m, 0), __shfl(m, 1), __shfl(m, 2), __shfl(m, 3));
    float4 rs = make_float4(__shfl(rcp, 0), __shfl(rcp, 1), __shfl(rcp, 2), __shfl(rcp, 3));
    for (int p = start + lane; p < end; p += 64) {
        float4 a = *(const float4*)(as1 + (size_t)edge_src[p] * 4);
        union { uint2 u; __half h[4]; } W;
        W.h[0] = __float2half(__expf(lrelu(a.x + ad.x) - mh.x) * rs.x);
        W.h[1] = __float2half(__expf(lrelu(a.y + ad.y) - mh.y) * rs.y);
        W.h[2] = __float2half(__expf(lrelu(a.z + ad.z) - mh.z) * rs.z);
        W.h[3] = __float2half(__expf(lrelu(a.w + ad.w) - mh.w) * rs.w);
        *(uint2*)(w4 + (size_t)p * 4) = W.u;
    }
}

__global__ __launch_bounds__(256) void stats2w_k(const int* __restrict__ edge_src,
                                                 const float* __restrict__ as2,
                                                 const float* __restrict__ ad2,
                                                 const int* __restrict__ offs,
                                                 const int* __restrict__ counts,
                                                 __half* __restrict__ w2, int N) {
    int lane = threadIdx.x & 63;
    int n = blockIdx.x * 4 + (threadIdx.x >> 6);
    if (n >= N) return;
    int start = offs[n];
    int end = start + counts[n];
    float adn = ad2[n];
    float m = -1e30f, s = 0.f;
    for (int p = start + lane; p < end; p += 64) {
        float e = lrelu(as2[edge_src[p]] + adn);
        float nm = fmaxf(m, e);
        s = s * __expf(m - nm) + __expf(e - nm);
        m = nm;
    }
#pragma unroll
    for (int i = 0; i < 6; ++i) {
        int msk = 1 << i;
        float om = __shfl_xor(m, msk);
        float os = __shfl_xor(s, msk);
        float nm = fmaxf(m, om);
        s = s * __expf(m - nm) + os * __expf(om - nm);
        m = nm;
    }
    float rn = 1.f / (s + 1e-16f);
    for (int p = start + lane; p < end; p += 64)
        w2[p] = __float2half(__expf(lrelu(as2[edge_src[p]] + adn) - m) * rn);
}

// ---------------------------------------------------------------- aggregate layer 1 (R12/R15-proven form)
__global__ __launch_bounds__(256) void agg1_k(const __half* __restrict__ h1,
                                              const __half* __restrict__ w4,
                                              const int* __restrict__ edge_src,
                                              const int* __restrict__ offs,
                                              const int* __restrict__ counts,
                                              const float* __restrict__ b1,
                                              __half* __restrict__ out1, int N) {
    int lane = threadIdx.x & 63;
    int n = blockIdx.x * 4 + (threadIdx.x >> 6);
    if (n >= N) return;
    int start = offs[n];
    int end = start + counts[n];
    float acc0 = 0.f, acc1 = 0.f, acc2 = 0.f, acc3 = 0.f;
    int p = start;
    for (; p + 7 < end; p += 8) {
        int s[8]; uint2 hw[8], ww[8];
#pragma unroll
        for (int i = 0; i < 8; ++i) s[i] = edge_src[p + i];
#pragma unroll
        for (int i = 0; i < 8; ++i) ww[i] = *(const uint2*)(w4 + (size_t)(p + i) * 4);
#pragma unroll
        for (int i = 0; i < 8; ++i) hw[i] = *(const uint2*)(h1 + (size_t)s[i] * 256 + lane * 4);
#pragma unroll
        for (int i = 0; i < 8; ++i) {
            union { uint2 u; __half h[4]; } U, W;
            U.u = hw[i]; W.u = ww[i];
            acc0 += __half2float(U.h[0]) * __half2float(W.h[0]);
            acc1 += __half2float(U.h[1]) * __half2float(W.h[1]);
            acc2 += __half2float(U.h[2]) * __half2float(W.h[2]);
            acc3 += __half2float(U.h[3]) * __half2float(W.h[3]);
        }
    }
    for (; p < end; ++p) {
        int s0 = edge_src[p];
        union { uint2 u; __half h[4]; } U0, W0;
        W0.u = *(const uint2*)(w4 + (size_t)p * 4);
        U0.u = *(const uint2*)(h1 + (size_t)s0 * 256 + lane * 4);
        acc0 += __half2float(U0.h[0]) * __half2float(W0.h[0]);
        acc1 += __half2float(U0.h[1]) * __half2float(W0.h[1]);
        acc2 += __half2float(U0.h[2]) * __half2float(W0.h[2]);
        acc3 += __half2float(U0.h[3]) * __half2float(W0.h[3]);
    }
    union { uint2 u; __half h[4]; } O;
    O.h[0] = __float2half(fmaxf(acc0 + b1[lane], 0.f));
    O.h[1] = __float2half(fmaxf(acc1 + b1[64 + lane], 0.f));
    O.h[2] = __float2half(fmaxf(acc2 + b1[128 + lane], 0.f));
    O.h[3] = __float2half(fmaxf(acc3 + b1[192 + lane], 0.f));
    *(uint2*)(out1 + (size_t)n * 256 + lane * 4) = O.u;
}

// ---------------------------------------------------------------- aggregate layer 2 (R12-proven form; fp16 out2)
__global__ __launch_bounds__(256) void agg2_k(const __half* __restrict__ h2,
                                              const __half* __restrict__ w2,
                                              const int* __restrict__ edge_src,
                                              const int* __restrict__ offs,
                                              const int* __restrict__ counts,
                                              const float* __restrict__ b2,
                                              __half* __restrict__ out2, int N) {
    int l32 = threadIdx.x & 31;
    int n = blockIdx.x * 8 + (threadIdx.x >> 5);
    if (n >= N) return;
    int start = offs[n];
    int end = start + counts[n];
    float ax = 0.f, ay = 0.f;
    int p = start;
    for (; p + 7 < end; p += 8) {
        int s[8]; __half wv8[8]; __half2 hv8[8];
#pragma unroll
        for (int i = 0; i < 8; ++i) s[i] = edge_src[p + i];
#pragma unroll
        for (int i = 0; i < 8; ++i) wv8[i] = w2[p + i];
#pragma unroll
        for (int i = 0; i < 8; ++i)
            hv8[i] = *(const __half2*)(h2 + (size_t)s[i] * 64 + l32 * 2);
#pragma unroll
        for (int i = 0; i < 8; ++i) {
            float w = __half2float(wv8[i]);
            float2 f = __half22float2(hv8[i]);
            ax += f.x * w; ay += f.y * w;
        }
    }
    for (; p < end; ++p) {
        float w = __half2float(w2[p]);
        float2 f = __half22float2(*(const __half2*)(h2 + (size_t)edge_src[p] * 64 + l32 * 2));
        ax += f.x * w; ay += f.y * w;
    }
    __half2 o;
    o.x = __float2half(fmaxf(ax + b2[l32 * 2], 0.f));
    o.y = __float2half(fmaxf(ay + b2[l32 * 2 + 1], 0.f));
    *(__half2*)(out2 + (size_t)n * 64 + l32 * 2) = o;
}

// ---------------------------------------------------------------- classifier head (fp16 input)
__global__ __launch_bounds__(256) void cls_k(const __half* __restrict__ hin,
                                             const float* __restrict__ Wc1,
                                             const float* __restrict__ bc1,
                                             const float* __restrict__ Wc2,
                                             const float* __restrict__ bc2,
                                             float* __restrict__ out, int N) {
    __shared__ float W1s[64 * 32];
    __shared__ float W2s[64];
    __shared__ float b1s[32];
    __shared__ float b2s[2];
    __shared__ float z[8][33];
    int t = threadIdx.x;
    for (int i = t; i < 2048; i += 256) W1s[i] = Wc1[i];
    if (t < 64) W2s[t] = Wc2[t];
    if (t < 32) b1s[t] = bc1[t];
    if (t < 2)  b2s[t] = bc2[t];
    __syncthreads();
    int nl = t >> 5, j = t & 31;
    int n = blockIdx.x * 8 + nl;
    float acc = b1s[j];
    if (n < N) {
        const __half* hr = hin + (size_t)n * 64;
#pragma unroll 8
        for (int l = 0; l < 64; ++l) acc += __half2float(hr[l]) * W1s[l * 32 + j];
    }
    z[nl][j] = fmaxf(acc, 0.f);
    __syncthreads();
    if (j < 2 && n < N) {
        float o = b2s[j];
#pragma unroll
        for (int q = 0; q < 32; ++q) o += z[nl][q] * W2s[q * 2 + j];
        out[(size_t)n * 2 + j] = o;
    }
}

// ---------------------------------------------------------------- launch
extern "C" void kernel_launch(void* const* d_in, const int* in_sizes, int n_in,
                              void* d_out, int out_size, void* d_ws, size_t ws_size,
                              hipStream_t stream) {
    const float* x      = (const float*)d_in[0];
    const int*   ei     = (const int*)d_in[1];
    const float* W1     = (const float*)d_in[2];
    const float* a_src1 = (const float*)d_in[3];
    const float* a_dst1 = (const float*)d_in[4];
    const float* b1     = (const float*)d_in[5];
    const float* W2     = (const float*)d_in[6];
    const float* a_src2 = (const float*)d_in[7];
    const float* a_dst2 = (const float*)d_in[8];
    const float* b2     = (const float*)d_in[9];
    const float* Wc1    = (const float*)d_in[10];
    const float* bc1    = (const float*)d_in[11];
    const float* Wc2    = (const float*)d_in[12];
    const float* bc2    = (const float*)d_in[13];

    char* ws = (char*)d_ws;
    size_t off = 0;
    auto alloc = [&](size_t bytes) -> void* {
        void* p = ws + off;
        off += (bytes + 255) & ~(size_t)255;
        return p;
    };
    int*       counts   = (int*)alloc((size_t)N_NODES * 4);   // contiguous with cursor
    int*       cursor   = (int*)alloc((size_t)N_NODES * 4);
    int*       offs     = (int*)alloc((size_t)N_NODES * 4);
    int*       chunks   = (int*)alloc(256);
    int*       edge_src = (int*)alloc((size_t)E_TOT * 4);
    float*     as1      = (float*)alloc((size_t)N_NODES * 16);
    float*     ad1      = (float*)alloc((size_t)N_NODES * 16);
    float*     as2      = (float*)alloc((size_t)N_NODES * 4);
    float*     ad2      = (float*)alloc((size_t)N_NODES * 4);
    __half*    w4       = (__half*)alloc((size_t)E_TOT * 8);        // fp16 L1 w; reused as L2 w
    _Float16*  Bt1      = (_Float16*)alloc((size_t)256 * 128 * 2);  // prepped W1
    _Float16*  Bt2      = (_Float16*)alloc((size_t)64 * 256 * 2);   // prepped W2
    __half*    h1h      = (__half*)alloc((size_t)N_NODES * 256 * 2);  // interleaved; reused as h2
    __half*    out1h    = (__half*)alloc((size_t)N_NODES * 256 * 2);  // interleaved
    __half*    out2h    = (__half*)alloc((size_t)N_NODES * 64 * 2);   // fp16 (cls input)
    __half*    h2h  = h1h;       // h1 dead after agg1
    __half*    w2b  = w4;        // w4 dead after agg1

    const int EB = (E_TOT + 255) / 256;
    const int NB4 = (N_NODES + 3) / 4;
    const int NB8 = (N_NODES + 7) / 8;
    const int NCH = (N_NODES + 1023) / 1024;  // 49
    const int MB = (N_NODES + 63) / 64;       // 782

    // counts and cursor are adjacent 256-aligned allocs: one memset covers both
    hipMemsetAsync(counts, 0, (char*)cursor - (char*)counts + (size_t)N_NODES * 4, stream);

    count_k<<<EB, 256, 0, stream>>>(ei, counts);
    scanA<<<NCH, 1024, 0, stream>>>(counts, offs, chunks, N_NODES);
    scanB<<<1, 64, 0, stream>>>(chunks, NCH);
    scanC<<<NCH, 1024, 0, stream>>>(offs, chunks, N_NODES);
    scatter_k<<<EB, 256, 0, stream>>>(ei, offs, cursor, edge_src);

    prepBoth_k<<<48, 256, 0, stream>>>(W1, W2, Bt1, Bt2);

    gemm_mfma<128, 256, 4, float, 1, 1><<<MB, 256, 0, stream>>>(
        x, Bt1, (_Float16*)h1h, a_src1, a_dst1, as1, ad1, N_NODES);
    stats1w_k<<<NB4, 256, 0, stream>>>(edge_src, as1, ad1, offs, counts, w4, N_NODES);
    agg1_k<<<NB4, 256, 0, stream>>>(h1h, w4, edge_src, offs, counts, b1, out1h, N_NODES);

    gemm_mfma<256, 64, 1, _Float16, 0, 2><<<MB, 256, 0, stream>>>(
        (const _Float16*)out1h, Bt2, (_Float16*)h2h, a_src2, a_dst2, as2, ad2, N_NODES);
    stats2w_k<<<NB4, 256, 0, stream>>>(edge_src, as2, ad2, offs, counts, w2b, N_NODES);
    agg2_k<<<NB8, 256, 0, stream>>>(h2h, w2b, edge_src, offs, counts, b2, out2h, N_NODES);

    cls_k<<<N_NODES / 8, 256, 0, stream>>>(out2h, Wc1, bc1, Wc2, bc2, (float*)d_out, N_NODES);
}

// Round 19
// 234.987 us; speedup vs baseline: 1.1827x; 1.0945x over previous
//
#include <hip/hip_runtime.h>
#include <hip/hip_fp16.h>

#define N_NODES 50000
#define N_EDGESx 600000
#define E_TOT   (N_EDGESx + N_NODES)   // 650000
#define NEG_SLOPE 0.2f

typedef _Float16 f16x4 __attribute__((ext_vector_type(4)));
typedef float f32x4 __attribute__((ext_vector_type(4)));

__device__ __forceinline__ float lrelu(float x) { return x > 0.f ? x : NEG_SLOPE * x; }

// ---------------------------------------------------------------- prep weights + edge count (fused, both LDS-free)
__global__ __launch_bounds__(256) void prepcnt_k(const float* __restrict__ W1,
                                                 const float* __restrict__ W2,
                                                 _Float16* __restrict__ Bt1,
                                                 _Float16* __restrict__ Bt2,
                                                 const int* __restrict__ ei,
                                                 int* __restrict__ counts) {
    int b = blockIdx.x;
    if (b < 32) {                       // W1: K=128, N=256, no BPERM
        constexpr int K = 128, N = 256;
        int q = b * 256 + threadIdx.x;
        int n = q & (N - 1);
        int k4 = q / N;
        f16x4 v;
#pragma unroll
        for (int i = 0; i < 4; ++i)
            v[i] = (_Float16)W1[(size_t)(k4 * 4 + i) * N + n];
        int idx = n * K + (((k4 >> 1) ^ (n & 15)) << 3) + ((k4 & 1) << 2);
        *(f16x4*)&Bt1[idx] = v;
    } else if (b < 48) {                // W2: K=256, N=64, BPERM (head interleave)
        constexpr int K = 256, N = 64;
        int q = (b - 32) * 256 + threadIdx.x;
        int n = q & (N - 1);
        int k4 = q / N;
        f16x4 v;
#pragma unroll
        for (int i = 0; i < 4; ++i) {
            int kg = k4 * 4 + i;
            int krow = (kg & 3) * 64 + (kg >> 2);
            v[i] = (_Float16)W2[(size_t)krow * N + n];
        }
        int idx = n * K + (((k4 >> 1) ^ (n & 15)) << 3) + ((k4 & 1) << 2);
        *(f16x4*)&Bt2[idx] = v;
    } else {                            // edge count
        int i = (b - 48) * 256 + threadIdx.x;
        if (i >= E_TOT) return;
        int dst = (i < N_EDGESx) ? ei[N_EDGESx + i] : (i - N_EDGESx);
        atomicAdd(&counts[dst], 1);
    }
}

// ---------------------------------------------------------------- CSR build
__global__ __launch_bounds__(1024) void scanA(const int* __restrict__ counts,
                                              int* __restrict__ offs,
                                              int* __restrict__ chunks, int N) {
    __shared__ int sdata[1024];
    int t = threadIdx.x;
    int g = blockIdx.x * 1024 + t;
    int v = (g < N) ? counts[g] : 0;
    sdata[t] = v;
    __syncthreads();
    for (int off = 1; off < 1024; off <<= 1) {
        int x = (t >= off) ? sdata[t - off] : 0;
        __syncthreads();
        sdata[t] += x;
        __syncthreads();
    }
    int incl = sdata[t];
    if (g < N) offs[g] = incl - v;           // exclusive within chunk
    if (t == 1023) chunks[blockIdx.x] = incl;
}

__global__ void scanB(int* chunks, int nch) {
    int lane = threadIdx.x & 63;
    int orig = (lane < nch) ? chunks[lane] : 0;
    int v = orig;
#pragma unroll
    for (int off = 1; off < 64; off <<= 1) {
        int u = __shfl_up(v, off);
        if (lane >= off) v += u;
    }
    if (lane < nch) chunks[lane] = v - orig;  // exclusive
}

__global__ __launch_bounds__(1024) void scanC(int* __restrict__ offs,
                                              const int* __restrict__ chunks, int N) {
    int g = blockIdx.x * 1024 + threadIdx.x;
    if (g < N) offs[g] += chunks[blockIdx.x];
}

__global__ __launch_bounds__(256) void scatter_k(const int* __restrict__ ei,
                                                 const int* __restrict__ offs,
                                                 int* __restrict__ cursor,
                                                 int* __restrict__ edge_src) {
    int i = blockIdx.x * 256 + threadIdx.x;
    if (i >= E_TOT) return;
    int src, dst;
    if (i < N_EDGESx) { src = ei[i]; dst = ei[N_EDGESx + i]; }
    else              { src = dst = i - N_EDGESx; }
    int pos = atomicAdd(&cursor[dst], 1);
    edge_src[offs[dst] + pos] = src;
}

// ---------------------------------------------------------------- MFMA GEMM (+fused alpha dots)
template<int K, int N, int CPW, typename AT, int CPERM, int ALPHA>
__global__ __launch_bounds__(256, 2) void gemm_mfma(const AT* __restrict__ A,
                                                    const _Float16* __restrict__ Bt,
                                                    _Float16* __restrict__ C,
                                                    const float* __restrict__ asrc,
                                                    const float* __restrict__ adst,
                                                    float* __restrict__ as_o,
                                                    float* __restrict__ ad_o, int M) {
    __shared__ __align__(16) _Float16 Ah[64 * K];
    __shared__ __align__(16) _Float16 Bh[N * K];
    const int t = threadIdx.x;
    const int row0 = blockIdx.x * 64;

#pragma unroll
    for (int q = t; q < 64 * K / 4; q += 256) {
        int r = q / (K / 4);
        int k4 = q % (K / 4);
        f16x4 v;
        int grow = row0 + r;
        if (grow < M) {
            if constexpr (sizeof(AT) == 4) {
                float4 f = *(const float4*)(A + (size_t)grow * K + k4 * 4);
                v[0] = (_Float16)f.x; v[1] = (_Float16)f.y;
                v[2] = (_Float16)f.z; v[3] = (_Float16)f.w;
            } else {
                v = *(const f16x4*)(A + (size_t)grow * K + k4 * 4);
            }
        } else {
            v[0] = v[1] = v[2] = v[3] = (_Float16)0.f;
        }
        int idx = r * K + (((k4 >> 1) ^ (r & 15)) << 3) + ((k4 & 1) << 2);
        *(f16x4*)&Ah[idx] = v;
    }
    // B staging: pure 16B copy (layout pre-swizzled in prepcnt_k)
#pragma unroll
    for (int q = t; q < N * K / 8; q += 256)
        ((uint4*)Bh)[q] = ((const uint4*)Bt)[q];
    __syncthreads();

    const int w = t >> 6;
    const int l = t & 63;
    const int lr = l & 15;
    const int g = l >> 4;

    f32x4 acc[4][CPW];
#pragma unroll
    for (int mt = 0; mt < 4; ++mt)
#pragma unroll
        for (int nt = 0; nt < CPW; ++nt)
            acc[mt][nt] = (f32x4){0.f, 0.f, 0.f, 0.f};

#pragma unroll
    for (int ks = 0; ks < K / 16; ++ks) {
        int k = ks * 16 + g * 4;
        f16x4 a[4], b[CPW];
#pragma unroll
        for (int mt = 0; mt < 4; ++mt) {
            int r = mt * 16 + lr;
            a[mt] = *(const f16x4*)&Ah[r * K + (((k >> 3) ^ (r & 15)) << 3) + (k & 7)];
        }
#pragma unroll
        for (int nt = 0; nt < CPW; ++nt) {
            int n = (w * CPW + nt) * 16 + lr;
            b[nt] = *(const f16x4*)&Bh[n * K + (((k >> 3) ^ (n & 15)) << 3) + (k & 7)];
        }
#pragma unroll
        for (int mt = 0; mt < 4; ++mt)
#pragma unroll
            for (int nt = 0; nt < CPW; ++nt)
                acc[mt][nt] = __builtin_amdgcn_mfma_f32_16x16x16f16(a[mt], b[nt],
                                                                   acc[mt][nt], 0, 0, 0);
    }

    if constexpr (CPERM) {
        // Ah is dead after the MFMA loop: reuse for a_src/a_dst staging + psums.
        float* A_s  = (float*)Ah;          // [256]
        float* A_d  = A_s + 256;           // [256]
        float* psum = A_d + 256;           // [64][4][8] = 2048 floats
        __syncthreads();
        _Float16* Cs = Bh;
#pragma unroll
        for (int mt = 0; mt < 4; ++mt)
#pragma unroll
            for (int q = 0; q < 4; ++q) {
                int row = mt * 16 + g * 4 + q;
#pragma unroll
                for (int nt = 0; nt < CPW; ++nt) {
                    int gcol = (w * CPW + nt) * 16 + lr;
                    int ocol = ((gcol & 63) << 2) | (gcol >> 6);
                    Cs[row * N + ocol] = (_Float16)acc[mt][nt][q];
                }
            }
        if constexpr (ALPHA == 1) { A_s[t] = asrc[t]; A_d[t] = adst[t]; }
        __syncthreads();
#pragma unroll
        for (int q = t; q < 64 * N / 8; q += 256) {
            int row = q / (N / 8);
            int c8 = q % (N / 8);
            int grow = row0 + row;
            if (grow < M)
                *(float4*)(C + (size_t)grow * N + c8 * 8) =
                    *(const float4*)&Cs[row * N + c8 * 8];
        }
        if constexpr (ALPHA == 1) {
            int row = t & 63, qr = t >> 6;
            float s[4] = {}, d[4] = {};
#pragma unroll
            for (int j = 0; j < 16; ++j) {
                int c = qr * 16 + j;
                union { uint2 u; __half h[4]; } U;
                U.u = *(const uint2*)&Cs[row * 256 + c * 4];
#pragma unroll
                for (int h = 0; h < 4; ++h) {
                    float f = __half2float(U.h[h]);
                    s[h] += f * A_s[h * 64 + c];
                    d[h] += f * A_d[h * 64 + c];
                }
            }
            float* ps = psum + (row * 4 + qr) * 8;
#pragma unroll
            for (int h = 0; h < 4; ++h) { ps[h] = s[h]; ps[4 + h] = d[h]; }
            __syncthreads();
            if (t < 64 && row0 + t < M) {
                float4 S = make_float4(0.f, 0.f, 0.f, 0.f);
                float4 D = make_float4(0.f, 0.f, 0.f, 0.f);
#pragma unroll
                for (int q2 = 0; q2 < 4; ++q2) {
                    float* ps2 = psum + (t * 4 + q2) * 8;
                    S.x += ps2[0]; S.y += ps2[1]; S.z += ps2[2]; S.w += ps2[3];
                    D.x += ps2[4]; D.y += ps2[5]; D.z += ps2[6]; D.w += ps2[7];
                }
                *(float4*)(as_o + (size_t)(row0 + t) * 4) = S;
                *(float4*)(ad_o + (size_t)(row0 + t) * 4) = D;
            }
        }
    } else {
#pragma unroll
        for (int mt = 0; mt < 4; ++mt)
#pragma unroll
            for (int q = 0; q < 4; ++q) {
                int grow = row0 + mt * 16 + g * 4 + q;
                if (grow >= M) continue;
#pragma unroll
                for (int nt = 0; nt < CPW; ++nt) {
                    int gcol = (w * CPW + nt) * 16 + lr;
                    C[(size_t)grow * N + gcol] = (_Float16)acc[mt][nt][q];
                }
            }
        if constexpr (ALPHA == 2) {
            __half* Ch  = (__half*)Ah;            // [64][64] = 8 KB
            float*  A_s = (float*)(Ch + 64 * 64); // [64]
            float*  A_d = A_s + 64;               // [64]
            float*  psum = A_d + 64;              // [64][4][2]
            __syncthreads();
#pragma unroll
            for (int mt = 0; mt < 4; ++mt)
#pragma unroll
                for (int q = 0; q < 4; ++q) {
                    int row = mt * 16 + g * 4 + q;
                    Ch[row * 64 + w * 16 + lr] = __float2half(acc[mt][0][q]);
                }
            if (t < 64) { A_s[t] = asrc[t]; A_d[t] = adst[t]; }
            __syncthreads();
            int row = t & 63, qr = t >> 6;
            float s = 0.f, d = 0.f;
#pragma unroll
            for (int j = 0; j < 16; ++j) {
                int c = qr * 16 + j;
                float f = __half2float(Ch[row * 64 + c]);
                s += f * A_s[c];
                d += f * A_d[c];
            }
            psum[(row * 4 + qr) * 2]     = s;
            psum[(row * 4 + qr) * 2 + 1] = d;
            __syncthreads();
            if (t < 64 && row0 + t < M) {
                float S = 0.f, D = 0.f;
#pragma unroll
                for (int q2 = 0; q2 < 4; ++q2) {
                    S += psum[(t * 4 + q2) * 2];
                    D += psum[(t * 4 + q2) * 2 + 1];
                }
                as_o[row0 + t] = S;
                ad_o[row0 + t] = D;
            }
        }
    }
}

// ---------------------------------------------------------------- stats + weight write (fp16 w)
// 4 nodes per wave (16 lanes/node) — mean degree ~13 means stride-64 wasted
// 80% of lanes; stride-16 puts 13/16 lanes to work.
__global__ __launch_bounds__(256) void stats1w_k(const int* __restrict__ edge_src,
                                                 const float* __restrict__ as1,
                                                 const float* __restrict__ ad1,
                                                 const int* __restrict__ offs,
                                                 const int* __restrict__ counts,
                                                 __half* __restrict__ w4, int N) {
    int t = threadIdx.x;
    int l16 = t & 15;
    int n = blockIdx.x * 16 + (t >> 4);
    if (n >= N) return;
    int start = offs[n];
    int end = start + counts[n];
    int h4 = l16 & 3;
    float4 ad = *(const float4*)(ad1 + (size_t)n * 4);
    float adh = h4 == 0 ? ad.x : h4 == 1 ? ad.y : h4 == 2 ? ad.z : ad.w;
    float m = -1e30f, s = 0.f;
    for (int p = start + (l16 >> 2); p < end; p += 4) {   // 4 edge-slots x 4 heads
        float e = lrelu(as1[(size_t)edge_src[p] * 4 + h4] + adh);
        float nm = fmaxf(m, e);
        s = s * __expf(m - nm) + __expf(e - nm);
        m = nm;
    }
#pragma unroll
    for (int i = 0; i < 2; ++i) {                 // reduce edge-slots: masks 4, 8
        int msk = 4 << i;
        float om = __shfl_xor(m, msk);
        float os = __shfl_xor(s, msk);
        float nm = fmaxf(m, om);
        s = s * __expf(m - nm) + os * __expf(om - nm);
        m = nm;
    }
    float rcp = 1.f / (s + 1e-16f);
    int gb = (t & 63) & ~15;   // group base lane within the wave
    float4 mh = make_float4(__shfl(m, gb), __shfl(m, gb + 1), __shfl(m, gb + 2), __shfl(m, gb + 3));
    float4 rs = make_float4(__shfl(rcp, gb), __shfl(rcp, gb + 1), __shfl(rcp, gb + 2), __shfl(rcp, gb + 3));
    for (int p = start + l16; p < end; p += 16) {
        float4 a = *(const float4*)(as1 + (size_t)edge_src[p] * 4);
        union { uint2 u; __half h[4]; } W;
        W.h[0] = __float2half(__expf(lrelu(a.x + ad.x) - mh.x) * rs.x);
        W.h[1] = __float2half(__expf(lrelu(a.y + ad.y) - mh.y) * rs.y);
        W.h[2] = __float2half(__expf(lrelu(a.z + ad.z) - mh.z) * rs.z);
        W.h[3] = __float2half(__expf(lrelu(a.w + ad.w) - mh.w) * rs.w);
        *(uint2*)(w4 + (size_t)p * 4) = W.u;
    }
}

__global__ __launch_bounds__(256) void stats2w_k(const int* __restrict__ edge_src,
                                                 const float* __restrict__ as2,
                                                 const float* __restrict__ ad2,
                                                 const int* __restrict__ offs,
                                                 const int* __restrict__ counts,
                                                 __half* __restrict__ w2, int N) {
    int t = threadIdx.x;
    int l16 = t & 15;
    int n = blockIdx.x * 16 + (t >> 4);
    if (n >= N) return;
    int start = offs[n];
    int end = start + counts[n];
    float adn = ad2[n];
    float m = -1e30f, s = 0.f;
    for (int p = start + l16; p < end; p += 16) {
        float e = lrelu(as2[edge_src[p]] + adn);
        float nm = fmaxf(m, e);
        s = s * __expf(m - nm) + __expf(e - nm);
        m = nm;
    }
#pragma unroll
    for (int i = 0; i < 4; ++i) {                 // butterfly within 16-lane group
        int msk = 1 << i;
        float om = __shfl_xor(m, msk);
        float os = __shfl_xor(s, msk);
        float nm = fmaxf(m, om);
        s = s * __expf(m - nm) + os * __expf(om - nm);
        m = nm;
    }
    float rn = 1.f / (s + 1e-16f);
    for (int p = start + l16; p < end; p += 16)
        w2[p] = __float2half(__expf(lrelu(as2[edge_src[p]] + adn) - m) * rn);
}

// ---------------------------------------------------------------- aggregate layer 1 (R12/R15-proven form)
__global__ __launch_bounds__(256) void agg1_k(const __half* __restrict__ h1,
                                              const __half* __restrict__ w4,
                                              const int* __restrict__ edge_src,
                                              const int* __restrict__ offs,
                                              const int* __restrict__ counts,
                                              const float* __restrict__ b1,
                                              __half* __restrict__ out1, int N) {
    int lane = threadIdx.x & 63;
    int n = blockIdx.x * 4 + (threadIdx.x >> 6);
    if (n >= N) return;
    int start = offs[n];
    int end = start + counts[n];
    float acc0 = 0.f, acc1 = 0.f, acc2 = 0.f, acc3 = 0.f;
    int p = start;
    for (; p + 7 < end; p += 8) {
        int s[8]; uint2 hw[8], ww[8];
#pragma unroll
        for (int i = 0; i < 8; ++i) s[i] = edge_src[p + i];
#pragma unroll
        for (int i = 0; i < 8; ++i) ww[i] = *(const uint2*)(w4 + (size_t)(p + i) * 4);
#pragma unroll
        for (int i = 0; i < 8; ++i) hw[i] = *(const uint2*)(h1 + (size_t)s[i] * 256 + lane * 4);
#pragma unroll
        for (int i = 0; i < 8; ++i) {
            union { uint2 u; __half h[4]; } U, W;
            U.u = hw[i]; W.u = ww[i];
            acc0 += __half2float(U.h[0]) * __half2float(W.h[0]);
            acc1 += __half2float(U.h[1]) * __half2float(W.h[1]);
            acc2 += __half2float(U.h[2]) * __half2float(W.h[2]);
            acc3 += __half2float(U.h[3]) * __half2float(W.h[3]);
        }
    }
    for (; p < end; ++p) {
        int s0 = edge_src[p];
        union { uint2 u; __half h[4]; } U0, W0;
        W0.u = *(const uint2*)(w4 + (size_t)p * 4);
        U0.u = *(const uint2*)(h1 + (size_t)s0 * 256 + lane * 4);
        acc0 += __half2float(U0.h[0]) * __half2float(W0.h[0]);
        acc1 += __half2float(U0.h[1]) * __half2float(W0.h[1]);
        acc2 += __half2float(U0.h[2]) * __half2float(W0.h[2]);
        acc3 += __half2float(U0.h[3]) * __half2float(W0.h[3]);
    }
    union { uint2 u; __half h[4]; } O;
    O.h[0] = __float2half(fmaxf(acc0 + b1[lane], 0.f));
    O.h[1] = __float2half(fmaxf(acc1 + b1[64 + lane], 0.f));
    O.h[2] = __float2half(fmaxf(acc2 + b1[128 + lane], 0.f));
    O.h[3] = __float2half(fmaxf(acc3 + b1[192 + lane], 0.f));
    *(uint2*)(out1 + (size_t)n * 256 + lane * 4) = O.u;
}

// ---------------------------------------------------------------- aggregate layer 2
// 4 nodes per wave: 16 lanes/node, each lane 4 channels via uint2 (8B);
// 4 independent segments in flight per wave; buffers stay ~16 VGPR.
__global__ __launch_bounds__(256) void agg2_k(const __half* __restrict__ h2,
                                              const __half* __restrict__ w2,
                                              const int* __restrict__ edge_src,
                                              const int* __restrict__ offs,
                                              const int* __restrict__ counts,
                                              const float* __restrict__ b2,
                                              __half* __restrict__ out2, int N) {
    int t = threadIdx.x;
    int l16 = t & 15;
    int n = blockIdx.x * 16 + (t >> 4);
    if (n >= N) return;
    int start = offs[n];
    int end = start + counts[n];
    float a0 = 0.f, a1 = 0.f, a2 = 0.f, a3 = 0.f;
    int p = start;
    for (; p + 7 < end; p += 8) {
        int s[8]; __half wv8[8]; uint2 hv8[8];
#pragma unroll
        for (int i = 0; i < 8; ++i) s[i] = edge_src[p + i];
#pragma unroll
        for (int i = 0; i < 8; ++i) wv8[i] = w2[p + i];
#pragma unroll
        for (int i = 0; i < 8; ++i)
            hv8[i] = *(const uint2*)(h2 + (size_t)s[i] * 64 + l16 * 4);
#pragma unroll
        for (int i = 0; i < 8; ++i) {
            union { uint2 u; __half h[4]; } U;
            U.u = hv8[i];
            float w = __half2float(wv8[i]);
            a0 += __half2float(U.h[0]) * w;
            a1 += __half2float(U.h[1]) * w;
            a2 += __half2float(U.h[2]) * w;
            a3 += __half2float(U.h[3]) * w;
        }
    }
    for (; p < end; ++p) {
        int s0 = edge_src[p];
        union { uint2 u; __half h[4]; } U;
        U.u = *(const uint2*)(h2 + (size_t)s0 * 64 + l16 * 4);
        float w = __half2float(w2[p]);
        a0 += __half2float(U.h[0]) * w;
        a1 += __half2float(U.h[1]) * w;
        a2 += __half2float(U.h[2]) * w;
        a3 += __half2float(U.h[3]) * w;
    }
    union { uint2 u; __half h[4]; } O;
    O.h[0] = __float2half(fmaxf(a0 + b2[l16 * 4],     0.f));
    O.h[1] = __float2half(fmaxf(a1 + b2[l16 * 4 + 1], 0.f));
    O.h[2] = __float2half(fmaxf(a2 + b2[l16 * 4 + 2], 0.f));
    O.h[3] = __float2half(fmaxf(a3 + b2[l16 * 4 + 3], 0.f));
    *(uint2*)(out2 + (size_t)n * 64 + l16 * 4) = O.u;
}

// ---------------------------------------------------------------- classifier head (fp16 input)
__global__ __launch_bounds__(256) void cls_k(const __half* __restrict__ hin,
                                             const float* __restrict__ Wc1,
                                             const float* __restrict__ bc1,
                                             const float* __restrict__ Wc2,
                                             const float* __restrict__ bc2,
                                             float* __restrict__ out, int N) {
    __shared__ float W1s[64 * 32];
    __shared__ float W2s[64];
    __shared__ float b1s[32];
    __shared__ float b2s[2];
    __shared__ float z[8][33];
    int t = threadIdx.x;
    for (int i = t; i < 2048; i += 256) W1s[i] = Wc1[i];
    if (t < 64) W2s[t] = Wc2[t];
    if (t < 32) b1s[t] = bc1[t];
    if (t < 2)  b2s[t] = bc2[t];
    __syncthreads();
    int nl = t >> 5, j = t & 31;
    int n = blockIdx.x * 8 + nl;
    float acc = b1s[j];
    if (n < N) {
        const __half* hr = hin + (size_t)n * 64;
#pragma unroll 8
        for (int l = 0; l < 64; ++l) acc += __half2float(hr[l]) * W1s[l * 32 + j];
    }
    z[nl][j] = fmaxf(acc, 0.f);
    __syncthreads();
    if (j < 2 && n < N) {
        float o = b2s[j];
#pragma unroll
        for (int q = 0; q < 32; ++q) o += z[nl][q] * W2s[q * 2 + j];
        out[(size_t)n * 2 + j] = o;
    }
}

// ---------------------------------------------------------------- launch
extern "C" void kernel_launch(void* const* d_in, const int* in_sizes, int n_in,
                              void* d_out, int out_size, void* d_ws, size_t ws_size,
                              hipStream_t stream) {
    const float* x      = (const float*)d_in[0];
    const int*   ei     = (const int*)d_in[1];
    const float* W1     = (const float*)d_in[2];
    const float* a_src1 = (const float*)d_in[3];
    const float* a_dst1 = (const float*)d_in[4];
    const float* b1     = (const float*)d_in[5];
    const float* W2     = (const float*)d_in[6];
    const float* a_src2 = (const float*)d_in[7];
    const float* a_dst2 = (const float*)d_in[8];
    const float* b2     = (const float*)d_in[9];
    const float* Wc1    = (const float*)d_in[10];
    const float* bc1    = (const float*)d_in[11];
    const float* Wc2    = (const float*)d_in[12];
    const float* bc2    = (const float*)d_in[13];

    char* ws = (char*)d_ws;
    size_t off = 0;
    auto alloc = [&](size_t bytes) -> void* {
        void* p = ws + off;
        off += (bytes + 255) & ~(size_t)255;
        return p;
    };
    int*       counts   = (int*)alloc((size_t)N_NODES * 4);   // contiguous with cursor
    int*       cursor   = (int*)alloc((size_t)N_NODES * 4);
    int*       offs     = (int*)alloc((size_t)N_NODES * 4);
    int*       chunks   = (int*)alloc(256);
    int*       edge_src = (int*)alloc((size_t)E_TOT * 4);
    float*     as1      = (float*)alloc((size_t)N_NODES * 16);
    float*     ad1      = (float*)alloc((size_t)N_NODES * 16);
    float*     as2      = (float*)alloc((size_t)N_NODES * 4);
    float*     ad2      = (float*)alloc((size_t)N_NODES * 4);
    __half*    w4       = (__half*)alloc((size_t)E_TOT * 8);        // fp16 L1 w; reused as L2 w
    _Float16*  Bt1      = (_Float16*)alloc((size_t)256 * 128 * 2);  // prepped W1
    _Float16*  Bt2      = (_Float16*)alloc((size_t)64 * 256 * 2);   // prepped W2
    __half*    h1h      = (__half*)alloc((size_t)N_NODES * 256 * 2);  // interleaved; reused as h2
    __half*    out1h    = (__half*)alloc((size_t)N_NODES * 256 * 2);  // interleaved
    __half*    out2h    = (__half*)alloc((size_t)N_NODES * 64 * 2);   // fp16 (cls input)
    __half*    h2h  = h1h;       // h1 dead after agg1
    __half*    w2b  = w4;        // w4 dead after agg1

    const int EB = (E_TOT + 255) / 256;
    const int NB4 = (N_NODES + 3) / 4;
    const int NB16 = (N_NODES + 15) / 16;     // 3125
    const int NCH = (N_NODES + 1023) / 1024;  // 49
    const int MB = (N_NODES + 63) / 64;       // 782

    // counts and cursor are adjacent 256-aligned allocs: one memset covers both
    hipMemsetAsync(counts, 0, (char*)cursor - (char*)counts + (size_t)N_NODES * 4, stream);

    prepcnt_k<<<48 + EB, 256, 0, stream>>>(W1, W2, Bt1, Bt2, ei, counts);
    scanA<<<NCH, 1024, 0, stream>>>(counts, offs, chunks, N_NODES);
    scanB<<<1, 64, 0, stream>>>(chunks, NCH);
    scanC<<<NCH, 1024, 0, stream>>>(offs, chunks, N_NODES);
    scatter_k<<<EB, 256, 0, stream>>>(ei, offs, cursor, edge_src);

    gemm_mfma<128, 256, 4, float, 1, 1><<<MB, 256, 0, stream>>>(
        x, Bt1, (_Float16*)h1h, a_src1, a_dst1, as1, ad1, N_NODES);
    stats1w_k<<<NB16, 256, 0, stream>>>(edge_src, as1, ad1, offs, counts, w4, N_NODES);
    agg1_k<<<NB4, 256, 0, stream>>>(h1h, w4, edge_src, offs, counts, b1, out1h, N_NODES);

    gemm_mfma<256, 64, 1, _Float16, 0, 2><<<MB, 256, 0, stream>>>(
        (const _Float16*)out1h, Bt2, (_Float16*)h2h, a_src2, a_dst2, as2, ad2, N_NODES);
    stats2w_k<<<NB16, 256, 0, stream>>>(edge_src, as2, ad2, offs, counts, w2b, N_NODES);
    agg2_k<<<NB16, 256, 0, stream>>>(h2h, w2b, edge_src, offs, counts, b2, out2h, N_NODES);

    cls_k<<<N_NODES / 8, 256, 0, stream>>>(out2h, Wc1, bc1, Wc2, bc2, (float*)d_out, N_NODES);
}